// Round 3
// baseline (3530.885 us; speedup 1.0000x reference)
//
#include <hip/hip_runtime.h>
#include <stdint.h>

#define FMAPD 56
#define WSD 7
#define SHIFTD 3
#define LD 49      // tokens per window
#define CD 96      // hidden
#define NHD 3
#define HDD 32     // head dim
#define M3D 288    // 3*C
#define FFDIM 384

using u16 = unsigned short;
using u32 = unsigned int;

__device__ __forceinline__ float b2f(u16 u) {
  union { u32 i; float f; } v; v.i = ((u32)u) << 16; return v.f;
}
__device__ __forceinline__ u16 f2b(float f) {
  union { float f; u32 i; } v; v.f = f;
  u32 r = v.i + 0x7fffu + ((v.i >> 16) & 1u);   // RNE
  return (u16)(r >> 16);
}
__device__ __forceinline__ void unp8(const uint4 p, float* o) {
  o[0] = b2f((u16)(p.x & 0xffffu)); o[1] = b2f((u16)(p.x >> 16));
  o[2] = b2f((u16)(p.y & 0xffffu)); o[3] = b2f((u16)(p.y >> 16));
  o[4] = b2f((u16)(p.z & 0xffffu)); o[5] = b2f((u16)(p.z >> 16));
  o[6] = b2f((u16)(p.w & 0xffffu)); o[7] = b2f((u16)(p.w >> 16));
}
// fp32 global 8-wide load
__device__ __forceinline__ void ld8g(const float* p, size_t i, float* o) {
  const float* f = p + i;
  float4 a = *(const float4*)f;
  float4 c = *(const float4*)(f + 4);
  o[0]=a.x; o[1]=a.y; o[2]=a.z; o[3]=a.w;
  o[4]=c.x; o[5]=c.y; o[6]=c.z; o[7]=c.w;
}
// LDS 8x bf16 load (internal buffers are bf16)
__device__ __forceinline__ void ld8s(const u16* p, int i, float* o) {
  uint4 v = *(const uint4*)(p + i);
  unp8(v, o);
}

// LayerNorm: s_xw (fp32) -> s_out (bf16). Caller must have synced before.
__device__ __forceinline__ void ln_phase(const float* s_xw, u16* s_out,
                                         const float* w, const float* bb,
                                         float* s_mu, float* s_rs, int tid)
{
  if (tid < LD) {
    float s = 0.f, s2 = 0.f;
    const float* r = s_xw + tid * CD;
#pragma unroll 8
    for (int c = 0; c < CD; ++c) { float v = r[c]; s += v; s2 += v * v; }
    float mu  = s * (1.f / CD);
    float var = s2 * (1.f / CD) - mu * mu;
    s_mu[tid] = mu;
    s_rs[tid] = rsqrtf(var + 1e-5f);
  }
  __syncthreads();
  for (int idx = tid; idx < LD * CD; idx += 256) {
    int t = idx / CD, c = idx - t * CD;
    float v = (s_xw[idx] - s_mu[t]) * s_rs[t] * w[c] + bb[c];
    s_out[idx] = f2b(v);
  }
  __syncthreads();
}

__global__ __launch_bounds__(256, 2)
void swin_fused(const float* __restrict__ gx,
                const float* __restrict__ w_qkv, const float* __restrict__ b_qkv,
                const float* __restrict__ w_out, const float* __restrict__ b_out,
                const float* __restrict__ w_ln1, const float* __restrict__ b_ln1,
                const float* __restrict__ w_ln2, const float* __restrict__ b_ln2,
                const float* __restrict__ w_ff1, const float* __restrict__ b_ff1,
                const float* __restrict__ w_ff2, const float* __restrict__ b_ff2,
                float* __restrict__ gout)
{
  __shared__ __align__(16) float s_xw[LD * CD];     // residual trunk, fp32
  __shared__ __align__(16) u16   s_h [LD * CD];     // LN out; later attn-out o
  __shared__ __align__(16) u16   s_sc[LD * M3D];    // qkv; later FFN hidden half
  __shared__ __align__(16) u16   s_att[LD * LD];    // scores / attn probs
  __shared__ float s_mu[LD];
  __shared__ float s_rs[LD];
  __shared__ int   s_id[LD];

  const int tid = threadIdx.x;
  const int blk = blockIdx.x;
  const int b   = blk >> 6;
  const int wr  = (blk >> 3) & 7;
  const int wc  = blk & 7;

  // P0: mask region ids (in shifted coords: rows/cols <49 | 49..52 | 53..55)
  if (tid < LD) {
    int i = tid / WSD, j = tid % WSD;
    int rp = wr * WSD + i, cp = wc * WSD + j;
    int ri = (rp < 49) ? 0 : ((rp < 53) ? 1 : 2);
    int ci = (cp < 49) ? 0 : ((cp < 53) ? 1 : 2);
    s_id[tid] = ri * 3 + ci;
  }

  // P1: load x -> s_xw (fp32). src pixel: ((wr*7+i+3)%56, (wc*7+j+3)%56)
  for (int idx = tid; idx < LD * 12; idx += 256) {
    int t = idx / 12, v = idx - (idx / 12) * 12;
    int row = wr * WSD + (t / WSD) + SHIFTD; if (row >= FMAPD) row -= FMAPD;
    int col = wc * WSD + (t % WSD) + SHIFTD; if (col >= FMAPD) col -= FMAPD;
    size_t base = ((size_t)b * (FMAPD * FMAPD) + row * FMAPD + col) * CD + v * 8;
    float f[8]; ld8g(gx, base, f);
#pragma unroll
    for (int q = 0; q < 8; ++q) s_xw[t * CD + v * 8 + q] = f[q];
  }
  __syncthreads();

  // P2: LN1 -> s_h (bf16)
  ln_phase(s_xw, s_h, w_ln1, b_ln1, s_mu, s_rs, tid);

  // P3: qkv = h @ qkv_w^T + qkv_b  -> s_sc [L][288] bf16
  for (int item = tid; item < 72 * 7; item += 256) {
    int m  = (item % 72) * 4;
    int t0 = (item / 72) * 7;
    float acc[4][7];
#pragma unroll
    for (int a = 0; a < 4; ++a) {
      float bv = b_qkv[m + a];
#pragma unroll
      for (int r = 0; r < 7; ++r) acc[a][r] = bv;
    }
    for (int cc = 0; cc < CD; cc += 8) {
      float hv[7][8];
#pragma unroll
      for (int r = 0; r < 7; ++r) ld8s(s_h, (t0 + r) * CD + cc, hv[r]);
#pragma unroll
      for (int a = 0; a < 4; ++a) {
        float wv[8]; ld8g(w_qkv, (size_t)(m + a) * CD + cc, wv);
#pragma unroll
        for (int q = 0; q < 8; ++q)
#pragma unroll
          for (int r = 0; r < 7; ++r) acc[a][r] += wv[q] * hv[r][q];
      }
    }
#pragma unroll
    for (int a = 0; a < 4; ++a)
#pragma unroll
      for (int r = 0; r < 7; ++r) s_sc[(t0 + r) * M3D + m + a] = f2b(acc[a][r]);
  }
  __syncthreads();

  // P4: attention per head; o overwrites s_h
  for (int hh = 0; hh < NHD; ++hh) {
    const int qo = hh * HDD, ko = CD + hh * HDD, vo = 2 * CD + hh * HDD;
    for (int idx = tid; idx < LD * LD; idx += 256) {
      int i = idx / LD, j = idx - i * LD;
      float acc = 0.f;
#pragma unroll
      for (int dd = 0; dd < HDD; dd += 8) {
        float qv[8], kv[8];
        ld8s(s_sc, i * M3D + qo + dd, qv);
        ld8s(s_sc, j * M3D + ko + dd, kv);
#pragma unroll
        for (int q = 0; q < 8; ++q) acc += qv[q] * kv[q];
      }
      acc = acc * 0.17677669529663687f;     // 1/sqrt(32)
      if (s_id[i] != s_id[j]) acc -= 1e9f;
      s_att[idx] = f2b(acc);
    }
    __syncthreads();
    if (tid < LD) {
      float mx = -3.0e38f;
      for (int j = 0; j < LD; ++j) mx = fmaxf(mx, b2f(s_att[tid * LD + j]));
      float den = 0.f;
      for (int j = 0; j < LD; ++j) {
        float e = __expf(b2f(s_att[tid * LD + j]) - mx);
        den += e;
        s_att[tid * LD + j] = f2b(e);
      }
      float inv = 1.0f / den;
      for (int j = 0; j < LD; ++j)
        s_att[tid * LD + j] = f2b(b2f(s_att[tid * LD + j]) * inv);
    }
    __syncthreads();
    for (int idx = tid; idx < LD * 4; idx += 256) {
      int i = idx >> 2, d8 = (idx & 3) * 8;
      float acc[8] = {0.f,0.f,0.f,0.f,0.f,0.f,0.f,0.f};
      for (int j = 0; j < LD; ++j) {
        float a = b2f(s_att[i * LD + j]);
        float vv[8]; ld8s(s_sc, j * M3D + vo + d8, vv);
#pragma unroll
        for (int q = 0; q < 8; ++q) acc[q] += a * vv[q];
      }
#pragma unroll
      for (int q = 0; q < 8; ++q) s_h[i * CD + hh * HDD + d8 + q] = f2b(acc[q]);
    }
    __syncthreads();
  }

  // P5: xw += o @ out_w^T + out_b
  for (int item = tid; item < 24 * 7; item += 256) {
    int c  = (item % 24) * 4;
    int t0 = (item / 24) * 7;
    float acc[4][7];
#pragma unroll
    for (int a = 0; a < 4; ++a) {
      float bv = b_out[c + a];
#pragma unroll
      for (int r = 0; r < 7; ++r) acc[a][r] = bv;
    }
    for (int cc = 0; cc < CD; cc += 8) {
      float ov[7][8];
#pragma unroll
      for (int r = 0; r < 7; ++r) ld8s(s_h, (t0 + r) * CD + cc, ov[r]);
#pragma unroll
      for (int a = 0; a < 4; ++a) {
        float wv[8]; ld8g(w_out, (size_t)(c + a) * CD + cc, wv);
#pragma unroll
        for (int q = 0; q < 8; ++q)
#pragma unroll
          for (int r = 0; r < 7; ++r) acc[a][r] += wv[q] * ov[r][q];
      }
    }
#pragma unroll
    for (int a = 0; a < 4; ++a)
#pragma unroll
      for (int r = 0; r < 7; ++r) s_xw[(t0 + r) * CD + c + a] += acc[a][r];
  }
  __syncthreads();

  // P6: LN2 -> s_h (bf16)
  ln_phase(s_xw, s_h, w_ln2, b_ln2, s_mu, s_rs, tid);

  // P7/P8: FFN in two 192-wide halves (s_sc reused as [L][192] hidden)
  for (int half = 0; half < 2; ++half) {
    const int fb = half * 192;
    for (int item = tid; item < 48 * 7; item += 256) {
      int f  = (item % 48) * 4;
      int t0 = (item / 48) * 7;
      float acc[4][7];
#pragma unroll
      for (int a = 0; a < 4; ++a) {
        float bv = b_ff1[fb + f + a];
#pragma unroll
        for (int r = 0; r < 7; ++r) acc[a][r] = bv;
      }
      for (int cc = 0; cc < CD; cc += 8) {
        float hv[7][8];
#pragma unroll
        for (int r = 0; r < 7; ++r) ld8s(s_h, (t0 + r) * CD + cc, hv[r]);
#pragma unroll
        for (int a = 0; a < 4; ++a) {
          float wv[8]; ld8g(w_ff1, (size_t)(fb + f + a) * CD + cc, wv);
#pragma unroll
          for (int q = 0; q < 8; ++q)
#pragma unroll
            for (int r = 0; r < 7; ++r) acc[a][r] += wv[q] * hv[r][q];
        }
      }
#pragma unroll
      for (int a = 0; a < 4; ++a)
#pragma unroll
        for (int r = 0; r < 7; ++r) {
          float v = acc[a][r];
          float g = 0.5f * v * (1.0f + erff(v * 0.70710678118654752f));  // exact GELU
          s_sc[(t0 + r) * 192 + f + a] = f2b(g);
        }
    }
    __syncthreads();
    for (int item = tid; item < 24 * 7; item += 256) {
      int c  = (item % 24) * 4;
      int t0 = (item / 24) * 7;
      float acc[4][7];
#pragma unroll
      for (int a = 0; a < 4; ++a) {
        float bv = half ? 0.f : b_ff2[c + a];
#pragma unroll
        for (int r = 0; r < 7; ++r) acc[a][r] = bv;
      }
      for (int cc = 0; cc < 192; cc += 8) {
        float fv[7][8];
#pragma unroll
        for (int r = 0; r < 7; ++r) ld8s(s_sc, (t0 + r) * 192 + cc, fv[r]);
#pragma unroll
        for (int a = 0; a < 4; ++a) {
          float wv[8]; ld8g(w_ff2, (size_t)(c + a) * FFDIM + fb + cc, wv);
#pragma unroll
          for (int q = 0; q < 8; ++q)
#pragma unroll
            for (int r = 0; r < 7; ++r) acc[a][r] += wv[q] * fv[r][q];
        }
      }
#pragma unroll
      for (int a = 0; a < 4; ++a)
#pragma unroll
        for (int r = 0; r < 7; ++r) s_xw[(t0 + r) * CD + c + a] += acc[a][r];
    }
    __syncthreads();
  }

  // P9: store fp32 (same pixel mapping as load) — output dtype is float32
  for (int idx = tid; idx < LD * 12; idx += 256) {
    int t = idx / 12, v = idx - (idx / 12) * 12;
    int row = wr * WSD + (t / WSD) + SHIFTD; if (row >= FMAPD) row -= FMAPD;
    int col = wc * WSD + (t % WSD) + SHIFTD; if (col >= FMAPD) col -= FMAPD;
    size_t base = ((size_t)b * (FMAPD * FMAPD) + row * FMAPD + col) * CD + v * 8;
    const float* src = s_xw + t * CD + v * 8;
    float4 p0 = make_float4(src[0], src[1], src[2], src[3]);
    float4 p1 = make_float4(src[4], src[5], src[6], src[7]);
    *(float4*)(gout + base)     = p0;
    *(float4*)(gout + base + 4) = p1;
  }
}

extern "C" void kernel_launch(void* const* d_in, const int* in_sizes, int n_in,
                              void* d_out, int out_size, void* d_ws, size_t ws_size,
                              hipStream_t stream) {
  swin_fused<<<8192, 256, 0, stream>>>(
      (const float*)d_in[0], (const float*)d_in[1], (const float*)d_in[2],
      (const float*)d_in[3], (const float*)d_in[4], (const float*)d_in[5],
      (const float*)d_in[6], (const float*)d_in[7], (const float*)d_in[8],
      (const float*)d_in[9], (const float*)d_in[10], (const float*)d_in[11],
      (const float*)d_in[12], (float*)d_out);
}